// Round 17
// baseline (321.834 us; speedup 1.0000x reference)
//
#include <hip/hip_runtime.h>
#include <hip/hip_bf16.h>

#define B_DIM 4096
#define M_DIM 768
#define N_DIM 16384
#define K_TOP 32
#define CAP 512
#define GBCAP 1536
#define THR_INIT 2.2f
#define RESCUE_MARGIN 0.09375f

typedef __bf16 bf16x8 __attribute__((ext_vector_type(8)));
typedef float  f32x4  __attribute__((ext_vector_type(4)));

static __device__ __forceinline__ unsigned short f2b(float f) {
  union { float f; unsigned u; } a; a.f = f;
  unsigned u = a.u;
  u += 0x7FFFu + ((u >> 16) & 1u);   // round-to-nearest-even
  return (unsigned short)(u >> 16);
}
static __device__ __forceinline__ float b2f(unsigned short h) {
  union { unsigned u; float f; } a; a.u = ((unsigned)h) << 16;
  return a.f;
}
static __device__ __forceinline__ unsigned pack_key(unsigned short h, int idx) {
  unsigned short k = (h & 0x8000) ? (unsigned short)~h : (unsigned short)(h | 0x8000);
  return ((unsigned)k << 16) | (unsigned)(idx & 0xFFFF);
}
static __device__ __forceinline__ float key_val(unsigned pk) {
  unsigned short k = (unsigned short)(pk >> 16);
  unsigned short h = (k & 0x8000) ? (unsigned short)(k ^ 0x8000) : (unsigned short)~k;
  return b2f(h);
}

// ---- Kernel 1: prep (center+cast X, cast W [+ cast D], zero counters) ------
__global__ __launch_bounds__(256) void prep_kernel(
    const float* __restrict__ X, const float* __restrict__ W,
    const float* __restrict__ Dmat,
    const float* __restrict__ pre_bias,
    unsigned short* __restrict__ Xcb, unsigned short* __restrict__ Wb,
    unsigned short* __restrict__ Db,   // may be null (ws too small)
    int* __restrict__ cnt)
{
  const int NX4 = B_DIM * M_DIM / 4;
  const int NW4 = N_DIM * M_DIM / 4;
  int stride = gridDim.x * blockDim.x;
  int i0 = blockIdx.x * blockDim.x + threadIdx.x;
  for (int i = i0; i < NX4; i += stride) {
    float4 x = reinterpret_cast<const float4*>(X)[i];
    int c4 = i % (M_DIM / 4);
    float4 pb = reinterpret_cast<const float4*>(pre_bias)[c4];
    ushort4 b;
    b.x = f2b(x.x - pb.x); b.y = f2b(x.y - pb.y);
    b.z = f2b(x.z - pb.z); b.w = f2b(x.w - pb.w);
    reinterpret_cast<ushort4*>(Xcb)[i] = b;
  }
  for (int i = i0; i < NW4; i += stride) {
    float4 x = reinterpret_cast<const float4*>(W)[i];
    ushort4 b; b.x = f2b(x.x); b.y = f2b(x.y); b.z = f2b(x.z); b.w = f2b(x.w);
    reinterpret_cast<ushort4*>(Wb)[i] = b;
  }
  if (Db) {
    for (int i = i0; i < NW4; i += stride) {
      float4 x = reinterpret_cast<const float4*>(Dmat)[i];
      ushort4 b; b.x = f2b(x.x); b.y = f2b(x.y); b.z = f2b(x.z); b.w = f2b(x.w);
      reinterpret_cast<ushort4*>(Db)[i] = b;
    }
  }
  for (int i = i0; i < B_DIM; i += stride) cnt[i] = 0;
}

// ---- Kernel 2: 256x256 encoder GEMM, 4-phase counted-vmcnt pipeline --------
// 512 threads = 8 waves (2M x 4N); BK=64; LDS = 128 KB dynamic double-buffer.
// Per K-tile: P1 ds_read bfr + af(m0-3), P3 ds_read af(m4-7); one 16KB
// half-tile staged per phase; vmcnt(6) (counted, never 0 mid-loop) per K-tile.
__global__ __launch_bounds__(512, 2) void gemm_enc(
    const unsigned short* __restrict__ A,   // Xc bf16 [4096][768]
    const unsigned short* __restrict__ Bw,  // W_enc bf16 [16384][768]
    const float* __restrict__ lbias,
    unsigned* __restrict__ lists,           // [4096][512] packed key|col
    int* __restrict__ cnt,                  // [4096]
    float* __restrict__ S)                  // dense S_: zero our 256x256 tile
{
  extern __shared__ char smem[];
  char* const As0 = smem;
  char* const As1 = smem + 32768;
  char* const Bs0 = smem + 65536;
  char* const Bs1 = smem + 98304;

  int t = threadIdx.x;
  int ln = t & 63;
  int wid = t >> 6;          // 0..7
  int wr = wid >> 2;         // 0..1
  int wc = wid & 3;          // 0..3

  int lid = blockIdx.x;
  int swz = (lid & 7) * 128 + (lid >> 3);   // 1024 blocks, bijective
  int tm = swz >> 6;         // 0..15
  int tn = swz & 63;         // 0..63
  int bb = tm * 256, bn = tn * 256;

  const int lrow = ln & 15;
  const int cb16 = (ln >> 4) << 4;
  const int cxor = (ln & 7) << 4;
  const int scolb = (((ln & 7) ^ (ln >> 3)) << 4);
  const int srl0 = (wid * 2 + 0) * 8 + (ln >> 3);
  const int srl1 = (wid * 2 + 1) * 8 + (ln >> 3);

#define STAGE_HT(kk, hh)                                                        \
  do {                                                                          \
    int buf_ = (kk) & 1;                                                        \
    const char* gb_ = ((hh) < 2) ? (const char*)A : (const char*)Bw;            \
    char* lb_ = ((hh) < 2) ? (buf_ ? As1 : As0) : (buf_ ? Bs1 : Bs0);           \
    int rb_ = (((hh) < 2) ? bb : bn) + ((hh) & 1) * 128;                        \
    lb_ += ((hh) & 1) * 16384;                                                  \
    size_t kb_ = (size_t)(kk) * 128;                                            \
    __builtin_amdgcn_global_load_lds(                                           \
        (__attribute__((address_space(1))) void*)(gb_ + (size_t)(rb_ + srl0) * 1536 + kb_ + scolb), \
        (__attribute__((address_space(3))) void*)(lb_ + (wid * 2 + 0) * 1024 + ln * 16), 16, 0, 0); \
    __builtin_amdgcn_global_load_lds(                                           \
        (__attribute__((address_space(1))) void*)(gb_ + (size_t)(rb_ + srl1) * 1536 + kb_ + scolb), \
        (__attribute__((address_space(3))) void*)(lb_ + (wid * 2 + 1) * 1024 + ln * 16), 16, 0, 0); \
  } while (0)

#define VMW6  asm volatile("s_waitcnt vmcnt(6)" ::: "memory")
#define VMW0  asm volatile("s_waitcnt vmcnt(0)" ::: "memory")
#define LGKM0 asm volatile("s_waitcnt lgkmcnt(0)" ::: "memory")
#define SB0   __builtin_amdgcn_sched_barrier(0)
#define BARR  __builtin_amdgcn_s_barrier()

  f32x4 acc[8][4] = {};
  bf16x8 af[4][2], bfr[4][2];

  // prologue: K0 all halves (A0,A1,B0,B1), then K1 B0,B1,A0
  STAGE_HT(0, 0); STAGE_HT(0, 1); STAGE_HT(0, 2); STAGE_HT(0, 3);
  STAGE_HT(1, 2); STAGE_HT(1, 3); STAGE_HT(1, 0);
  VMW6; SB0; BARR; SB0;

  for (int k = 0; k < 12; ++k) {
    char* AsK = (k & 1) ? As1 : As0;
    char* BsK = (k & 1) ? Bs1 : Bs0;
    // ---- P1: read bfr(8) + af m0-3 (8); stage A1(k+1); MFMA m0,m1 ----
#pragma unroll
    for (int n = 0; n < 4; ++n)
#pragma unroll
      for (int g = 0; g < 2; ++g)
        bfr[n][g] = *reinterpret_cast<const bf16x8*>(
            BsK + (size_t)(wc * 64 + n * 16 + lrow) * 128 + ((g * 64 + cb16) ^ cxor));
#pragma unroll
    for (int mm = 0; mm < 4; ++mm)
#pragma unroll
      for (int g = 0; g < 2; ++g)
        af[mm][g] = *reinterpret_cast<const bf16x8*>(
            AsK + (size_t)(wr * 128 + mm * 16 + lrow) * 128 + ((g * 64 + cb16) ^ cxor));
    if (k + 1 < 12) STAGE_HT(k + 1, 1);
    LGKM0; SB0;
#pragma unroll
    for (int mm = 0; mm < 2; ++mm)
#pragma unroll
      for (int n = 0; n < 4; ++n)
#pragma unroll
        for (int g = 0; g < 2; ++g)
          acc[mm][n] = __builtin_amdgcn_mfma_f32_16x16x32_bf16(af[mm][g], bfr[n][g], acc[mm][n], 0, 0, 0);
    BARR; SB0;
    // ---- P2: stage B0(k+2); MFMA m2,m3 ----
    if (k + 2 < 12) STAGE_HT(k + 2, 2);
#pragma unroll
    for (int mm = 2; mm < 4; ++mm)
#pragma unroll
      for (int n = 0; n < 4; ++n)
#pragma unroll
        for (int g = 0; g < 2; ++g)
          acc[mm][n] = __builtin_amdgcn_mfma_f32_16x16x32_bf16(af[mm][g], bfr[n][g], acc[mm][n], 0, 0, 0);
    BARR; SB0;
    // ---- P3: read af m4-7; stage B1(k+2); MFMA m4,m5 ----
#pragma unroll
    for (int mm = 0; mm < 4; ++mm)
#pragma unroll
      for (int g = 0; g < 2; ++g)
        af[mm][g] = *reinterpret_cast<const bf16x8*>(
            AsK + (size_t)(wr * 128 + 64 + mm * 16 + lrow) * 128 + ((g * 64 + cb16) ^ cxor));
    if (k + 2 < 12) STAGE_HT(k + 2, 3);
    LGKM0; SB0;
#pragma unroll
    for (int mm = 0; mm < 2; ++mm)
#pragma unroll
      for (int n = 0; n < 4; ++n)
#pragma unroll
        for (int g = 0; g < 2; ++g)
          acc[4 + mm][n] = __builtin_amdgcn_mfma_f32_16x16x32_bf16(af[mm][g], bfr[n][g], acc[4 + mm][n], 0, 0, 0);
    BARR; SB0;
    // ---- P4: stage A0(k+2); MFMA m6,m7; counted vmcnt; barrier ----
    if (k + 2 < 12) STAGE_HT(k + 2, 0);
#pragma unroll
    for (int mm = 2; mm < 4; ++mm)
#pragma unroll
      for (int n = 0; n < 4; ++n)
#pragma unroll
        for (int g = 0; g < 2; ++g)
          acc[4 + mm][n] = __builtin_amdgcn_mfma_f32_16x16x32_bf16(af[mm][g], bfr[n][g], acc[4 + mm][n], 0, 0, 0);
    if (k < 10) { VMW6; } else { VMW0; }
    SB0; BARR; SB0;
  }

  // fire-and-forget: zero this block's 256x256 S_ sub-tile (NT, coalesced)
  {
    f32x4 z = {0.f, 0.f, 0.f, 0.f};
    int r0 = t >> 6;            // 0..7
    int c4 = t & 63;            // f32x4 col 0..63
#pragma unroll
    for (int p = 0; p < 32; ++p) {
      int row = p * 8 + r0;
      __builtin_nontemporal_store(z,
          reinterpret_cast<f32x4*>(S + (size_t)(bb + row) * N_DIM + bn) + c4);
    }
  }
  __syncthreads();   // drain; staging LDS now dead -> alias collect arrays

  unsigned* bl_pk = reinterpret_cast<unsigned*>(smem);           //  6144 B
  int* bl_row = reinterpret_cast<int*>(smem + 6144);             //  6144 B
  int* bl_slot = reinterpret_cast<int*>(smem + 12288);           //  6144 B
  int* rcnt = reinterpret_cast<int*>(smem + 18432);              //  1024 B
  int* rbase = reinterpret_cast<int*>(smem + 19456);             //  1024 B
  int* bcnt = reinterpret_cast<int*>(smem + 20480);
  if (t < 256) rcnt[t] = 0;
  if (t == 0) *bcnt = 0;
  __syncthreads();

  // wave-aggregated LDS append of candidates (v > THR)
#pragma unroll
  for (int n = 0; n < 4; ++n) {
    int col = bn + wc * 64 + n * 16 + (ln & 15);
    float lb = lbias[col];
#pragma unroll
    for (int m = 0; m < 8; ++m) {
      int rl0 = wr * 128 + m * 16 + (ln >> 4) * 4;
#pragma unroll
      for (int j = 0; j < 4; ++j) {
        float v = acc[m][n][j] + lb;
        bool pred = (v > THR_INIT);
        unsigned long long mask = __ballot(pred);
        if (pred) {
          int lead = __ffsll((unsigned long long)mask) - 1;
          int base = 0;
          if (ln == lead) base = atomicAdd(bcnt, (int)__popcll(mask));
          base = __shfl(base, lead);
          int p = base + (int)__popcll(mask & ((1ull << ln) - 1ull));
          if (p < GBCAP) {
            bl_pk[p] = pack_key(f2b(v), col);
            bl_row[p] = rl0 + j;
          }
        }
      }
    }
  }
  __syncthreads();

  int nb = *bcnt; if (nb > GBCAP) nb = GBCAP;
  for (int e = t; e < nb; e += 512)
    bl_slot[e] = atomicAdd(&rcnt[bl_row[e]], 1);
  __syncthreads();

  if (t < 256) {
    int c = rcnt[t];
    int add = c + ((*bcnt > GBCAP) ? 100000 : 0);   // overflow -> fallback
    rbase[t] = add ? atomicAdd(&cnt[bb + t], add) : 0;
  }
  __syncthreads();

  for (int e = t; e < nb; e += 512) {
    int rl = bl_row[e];
    int g = rbase[rl] + bl_slot[e];
    if (g < CAP) lists[(size_t)(bb + rl) * CAP + g] = bl_pk[e];
  }
#undef STAGE_HT
#undef VMW6
#undef VMW0
#undef LGKM0
#undef SB0
#undef BARR
}

// ---- Kernel 3: select (safe/borderline split) + scatter + decode -----------
template<bool BF16D>
__global__ __launch_bounds__(256) void select_output(
    const unsigned* __restrict__ lists, const int* __restrict__ cnt,
    const float* __restrict__ X, const float* __restrict__ pbias,
    const float* __restrict__ W,            // f32 W_enc
    const unsigned short* __restrict__ Xcb, // bf16 inputs (fallback only)
    const unsigned short* __restrict__ Wb,
    const float* __restrict__ lbias,
    const float* __restrict__ Dmat,         // f32 D
    const unsigned short* __restrict__ Db,  // bf16 D (BF16D path)
    float* __restrict__ S, float* __restrict__ Xout)
{
  __shared__ unsigned list[CAP];
  __shared__ float xrow[M_DIM];
  __shared__ int ridx[256];
  __shared__ double rval[256];
  __shared__ float s_v32;
  __shared__ int s_rc, s_cnt, s_ns;
  __shared__ int si[K_TOP];
  __shared__ float sv[K_TOP];

  int b = blockIdx.x;
  int t = threadIdx.x;
  int ln = t & 63, w = t >> 6;

  for (int i = t; i < M_DIM; i += 256)
    xrow[i] = X[(size_t)b * M_DIM + i] - pbias[i];
  if (t < K_TOP) { si[t] = t; sv[t] = 0.f; }
  if (t == 0) { s_v32 = -1.0e30f; s_rc = 0; s_ns = 0; }

  int count = cnt[b];
  int nc;
  if (count >= 48 && count <= CAP) {
    for (int i = t; i < count; i += 256) list[i] = lists[(size_t)b * CAP + i];
    nc = count;
    __syncthreads();
  } else {
    // near-impossible fallback: recompute bf16-proxy row, adaptive collect
    float pv[N_DIM / 256];
#pragma unroll 1
    for (int q = 0; q < N_DIM / 256; ++q) {
      int n = t + q * 256;
      const unsigned short* wrp = Wb + (size_t)n * M_DIM;
      const unsigned short* xbp = Xcb + (size_t)b * M_DIM;
      float s = 0.f;
      for (int k = 0; k < M_DIM; ++k) s = fmaf(b2f(xbp[k]), b2f(wrp[k]), s);
      pv[q] = s + lbias[n];
    }
    float thr = THR_INIT;
    for (int it = 0; it < 8; ++it) {
      __syncthreads();
      if (t == 0) s_cnt = 0;
      __syncthreads();
#pragma unroll 1
      for (int q = 0; q < N_DIM / 256; ++q) {
        if (pv[q] > thr) {
          int p = atomicAdd(&s_cnt, 1);
          if (p < CAP) list[p] = pack_key(f2b(pv[q]), t + q * 256);
        }
      }
      __syncthreads();
      int c = s_cnt;
      if (c > CAP)      { thr += 0.35f; continue; }
      else if (c < 48)  { thr -= 0.60f; continue; }
      break;
    }
    nc = s_cnt < CAP ? s_cnt : CAP;
    __syncthreads();
  }

  // rank by packed key -> v32 (keys unique; exactly one has rank K_TOP-1)
  for (int q = t; q < nc; q += 256) {
    unsigned me = list[q];
    int r = 0;
    for (int j = 0; j < nc; ++j) r += (list[j] > me);
    if (r == K_TOP - 1) s_v32 = key_val(me);
  }
  __syncthreads();

  float v32 = s_v32;
  float vplus = v32 + RESCUE_MARGIN;
  float vminus = v32 - RESCUE_MARGIN;

  // partition: safe -> direct slot (pk-rank among safe); borderline -> dots
  for (int q = t; q < nc; q += 256) {
    unsigned me = list[q];
    float kv = key_val(me);
    if (kv > vplus) {
      int r = 0;
      for (int j = 0; j < nc; ++j) {
        unsigned o = list[j];
        if (o > me && key_val(o) > vplus) ++r;
      }
      si[r] = (int)(me & 0xFFFF);
      sv[r] = kv;
      atomicAdd(&s_ns, 1);
    } else if (kv >= vminus) {
      int p = atomicAdd(&s_rc, 1);
      if (p < 256) ridx[p] = (int)(me & 0xFFFF);
    }
  }
  __syncthreads();
  int ns = s_ns;
  int nr = s_rc < 256 ? s_rc : 256;
  int need = K_TOP - ns;

  // exact f64 dot per borderline candidate (one wave each), float4 W reads
  for (int cc = w; cc < nr; cc += 4) {
    int n = ridx[cc];
    const f32x4* w4 = reinterpret_cast<const f32x4*>(W + (size_t)n * M_DIM);
    double s = 0.0;
#pragma unroll
    for (int j = 0; j < M_DIM / 256; ++j) {
      int i4 = ln + 64 * j;
      f32x4 wv = w4[i4];
      int k0 = i4 * 4;
      s += (double)xrow[k0]     * (double)wv.x;
      s += (double)xrow[k0 + 1] * (double)wv.y;
      s += (double)xrow[k0 + 2] * (double)wv.z;
      s += (double)xrow[k0 + 3] * (double)wv.w;
    }
    for (int off = 32; off > 0; off >>= 1) s += __shfl_down(s, off);
    if (ln == 0) rval[cc] = s + (double)lbias[n];
  }
  __syncthreads();

  // borderline top-(need) by (val desc, idx asc); ranks unique
  if (t < nr) {
    double mv = rval[t];
    int mi = ridx[t];
    int r = 0;
    for (int j = 0; j < nr; ++j) {
      double v = rval[j];
      if (v > mv || (v == mv && ridx[j] < mi)) ++r;
    }
    if (r < need) {
      si[ns + r] = mi;
      sv[ns + r] = fmaxf((float)mv, 0.0f);
    }
  }
  __syncthreads();

  // scatter the 32 values into the pre-zeroed S_ row
  if (t < K_TOP)
    S[(size_t)b * N_DIM + si[t]] = sv[t];

  // decode: X_[b,:] = sum_j val_j * D[idx_j,:] + pre_bias
  if constexpr (BF16D) {
    if (t < M_DIM / 8) {
      float a[8] = {0.f, 0.f, 0.f, 0.f, 0.f, 0.f, 0.f, 0.f};
#pragma unroll 4
      for (int j = 0; j < K_TOP; ++j) {
        float v = sv[j];
        uint4 dv = reinterpret_cast<const uint4*>(Db + (size_t)si[j] * M_DIM)[t];
        const unsigned* du = reinterpret_cast<const unsigned*>(&dv);
#pragma unroll
        for (int e = 0; e < 4; ++e) {
          a[2 * e]     = fmaf(v, b2f((unsigned short)(du[e] & 0xFFFFu)), a[2 * e]);
          a[2 * e + 1] = fmaf(v, b2f((unsigned short)(du[e] >> 16)),     a[2 * e + 1]);
        }
      }
      float* xo = Xout + (size_t)b * M_DIM + t * 8;
      f32x4 o0, o1;
      o0.x = a[0] + pbias[t * 8 + 0]; o0.y = a[1] + pbias[t * 8 + 1];
      o0.z = a[2] + pbias[t * 8 + 2]; o0.w = a[3] + pbias[t * 8 + 3];
      o1.x = a[4] + pbias[t * 8 + 4]; o1.y = a[5] + pbias[t * 8 + 5];
      o1.z = a[6] + pbias[t * 8 + 6]; o1.w = a[7] + pbias[t * 8 + 7];
      __builtin_nontemporal_store(o0, reinterpret_cast<f32x4*>(xo));
      __builtin_nontemporal_store(o1, reinterpret_cast<f32x4*>(xo) + 1);
    }
  } else {
    if (t < M_DIM / 4) {
      f32x4 a = {0.f, 0.f, 0.f, 0.f};
#pragma unroll 4
      for (int j = 0; j < K_TOP; ++j) {
        float v = sv[j];
        f32x4 d = reinterpret_cast<const f32x4*>(Dmat + (size_t)si[j] * M_DIM)[t];
        a.x = fmaf(v, d.x, a.x); a.y = fmaf(v, d.y, a.y);
        a.z = fmaf(v, d.z, a.z); a.w = fmaf(v, d.w, a.w);
      }
      f32x4 p = reinterpret_cast<const f32x4*>(pbias)[t];
      a.x += p.x; a.y += p.y; a.z += p.z; a.w += p.w;
      __builtin_nontemporal_store(a, reinterpret_cast<f32x4*>(Xout + (size_t)b * M_DIM) + t);
    }
  }
}

extern "C" void kernel_launch(void* const* d_in, const int* in_sizes, int n_in,
                              void* d_out, int out_size, void* d_ws, size_t ws_size,
                              hipStream_t stream) {
  const float* X  = (const float*)d_in[0];
  const float* Dm = (const float*)d_in[1];
  const float* We = (const float*)d_in[2];
  const float* lb = (const float*)d_in[3];
  const float* pb = (const float*)d_in[4];

  float* S  = (float*)d_out;                        // S_ region, f32 [4096][16384]
  float* Xo = S + (size_t)B_DIM * N_DIM;            // X_ region, f32 [4096][768]

  // ws layout (base 39,862,272 B proven; Db optional +25,165,824 B)
  char* ws = (char*)d_ws;
  unsigned short* Xcb   = (unsigned short*)(ws);               //  6,291,456 B
  unsigned short* Wb    = (unsigned short*)(ws +  6291456);    // 25,165,824 B
  unsigned*       lists = (unsigned*)      (ws + 31457280);    //  8,388,608 B
  int*            cnt   = (int*)           (ws + 39845888);    //     16,384 B
  const size_t DB_OFF = 39862272ull;
  const size_t WS_NEED_DB = DB_OFF + 25165824ull;              // 65,028,096 B
  bool useDb = (ws_size >= WS_NEED_DB);
  unsigned short* Db = useDb ? (unsigned short*)(ws + DB_OFF) : nullptr;

  prep_kernel<<<dim3(1024), dim3(256), 0, stream>>>(X, We, Dm, pb, Xcb, Wb, Db, cnt);
  gemm_enc<<<dim3(1024), dim3(512), 131072, stream>>>(Xcb, Wb, lb, lists, cnt, S);
  if (useDb)
    select_output<true><<<dim3(4096), dim3(256), 0, stream>>>(
        lists, cnt, X, pb, We, Xcb, Wb, lb, Dm, Db, S, Xo);
  else
    select_output<false><<<dim3(4096), dim3(256), 0, stream>>>(
        lists, cnt, X, pb, We, Xcb, Wb, lb, Dm, nullptr, S, Xo);
}

// Round 18
// 289.479 us; speedup vs baseline: 1.1118x; 1.1118x over previous
//
#include <hip/hip_runtime.h>
#include <hip/hip_bf16.h>

#define B_DIM 4096
#define M_DIM 768
#define N_DIM 16384
#define K_TOP 32
#define CAP 512
#define BCAP 512
#define THR_INIT 2.2f
#define RESCUE_MARGIN 0.09375f

typedef __bf16 bf16x8 __attribute__((ext_vector_type(8)));
typedef float  f32x4  __attribute__((ext_vector_type(4)));

static __device__ __forceinline__ unsigned short f2b(float f) {
  union { float f; unsigned u; } a; a.f = f;
  unsigned u = a.u;
  u += 0x7FFFu + ((u >> 16) & 1u);   // round-to-nearest-even
  return (unsigned short)(u >> 16);
}
static __device__ __forceinline__ float b2f(unsigned short h) {
  union { unsigned u; float f; } a; a.u = ((unsigned)h) << 16;
  return a.f;
}
// monotonic 16-bit key in high bits, col idx in low bits
static __device__ __forceinline__ unsigned pack_key(unsigned short h, int idx) {
  unsigned short k = (h & 0x8000) ? (unsigned short)~h : (unsigned short)(h | 0x8000);
  return ((unsigned)k << 16) | (unsigned)(idx & 0xFFFF);
}
static __device__ __forceinline__ float key_val(unsigned pk) {
  unsigned short k = (unsigned short)(pk >> 16);
  unsigned short h = (k & 0x8000) ? (unsigned short)(k ^ 0x8000) : (unsigned short)~k;
  return b2f(h);
}

// ------------- Kernel 1: prep (center+cast X, cast W, zero counters) --------
__global__ __launch_bounds__(256) void prep_kernel(
    const float* __restrict__ X, const float* __restrict__ W,
    const float* __restrict__ pre_bias,
    unsigned short* __restrict__ Xcb, unsigned short* __restrict__ Wb,
    int* __restrict__ cnt)
{
  const int NX4 = B_DIM * M_DIM / 4;
  const int NW4 = N_DIM * M_DIM / 4;
  int stride = gridDim.x * blockDim.x;
  int i0 = blockIdx.x * blockDim.x + threadIdx.x;
  for (int i = i0; i < NX4; i += stride) {
    float4 x = reinterpret_cast<const float4*>(X)[i];
    int c4 = i % (M_DIM / 4);
    float4 pb = reinterpret_cast<const float4*>(pre_bias)[c4];
    ushort4 b;
    b.x = f2b(x.x - pb.x); b.y = f2b(x.y - pb.y);
    b.z = f2b(x.z - pb.z); b.w = f2b(x.w - pb.w);
    reinterpret_cast<ushort4*>(Xcb)[i] = b;
  }
  for (int i = i0; i < NW4; i += stride) {
    float4 x = reinterpret_cast<const float4*>(W)[i];
    ushort4 b; b.x = f2b(x.x); b.y = f2b(x.y); b.z = f2b(x.z); b.w = f2b(x.w);
    reinterpret_cast<ushort4*>(Wb)[i] = b;
  }
  for (int i = i0; i < B_DIM; i += stride) cnt[i] = 0;
}

// ---- Kernel 2: encoder GEMM (BK=64, XOR-swizzled LDS, r8 XCD swizzle) ------
// + fused fire-and-forget NT zeroing of this block's 128x128 S_ sub-tile
//   at the K-loop TAIL (measured-best placement: 186 us, r11/r16).
__global__ __launch_bounds__(256, 3) void gemm_enc(
    const unsigned short* __restrict__ A,   // Xc bf16 [4096][768]
    const unsigned short* __restrict__ Bw,  // W_enc bf16 [16384][768]
    const float* __restrict__ lbias,
    unsigned* __restrict__ lists,           // [4096][512] packed key|col
    int* __restrict__ cnt,                  // [4096]
    float* __restrict__ S)                  // dense S_ region: zero our subtile
{
  __shared__ __align__(16) unsigned short As[128 * 64];
  __shared__ __align__(16) unsigned short Bs[128 * 64];
  __shared__ unsigned bl_pk[BCAP];
  __shared__ int bl_row[BCAP];
  __shared__ int bl_slot[BCAP];
  __shared__ int rcnt[128];
  __shared__ int rbase[128];
  __shared__ int bcnt;

  int t = threadIdx.x;
  int ln = t & 63;
  int w = t >> 6;
  int wr = w >> 1, wc = w & 1;

  if (t == 0) bcnt = 0;
  if (t < 128) rcnt[t] = 0;

  // round-8 XCD swizzle: contiguous chunk per XCD, tx fast within ty
  int lid = blockIdx.x;
  int swz = (lid & 7) * (4096 / 8) + (lid >> 3);
  int ty = swz >> 7;        // 0..31
  int tx = swz & 127;       // 0..127
  int bb = ty * 128, bn = tx * 128;

  int srow = t >> 3;                          // 0..31 local row in 32-row chunk
  int scol = (((t & 7) ^ ((t >> 3) & 7)) << 4);
  const char* gAb = (const char*)A  + (size_t)(bb + srow) * (M_DIM * 2) + scol;
  const char* gBb = (const char*)Bw + (size_t)(bn + srow) * (M_DIM * 2) + scol;
  char* lA = (char*)As + t * 16;
  char* lB = (char*)Bs + t * 16;
  const int CH = 32 * M_DIM * 2;              // 32-row global chunk stride

  f32x4 acc[4][4] = {};

  int cxor = (ln & 7) << 4;
  int cb16 = (ln >> 4) << 4;
  int ra = wr * 64 + (ln & 15);
  int rb = wc * 64 + (ln & 15);

  for (int kb = 0; kb < M_DIM * 2; kb += 128) {   // 64 cols * 2B per step
#pragma unroll
    for (int q = 0; q < 4; ++q) {
      __builtin_amdgcn_global_load_lds(
          (__attribute__((address_space(1))) void*)(gAb + q * CH + kb),
          (__attribute__((address_space(3))) void*)(lA + q * 4096), 16, 0, 0);
      __builtin_amdgcn_global_load_lds(
          (__attribute__((address_space(1))) void*)(gBb + q * CH + kb),
          (__attribute__((address_space(3))) void*)(lB + q * 4096), 16, 0, 0);
    }
    __syncthreads();

#pragma unroll
    for (int g = 0; g < 2; ++g) {
      int cb = ((g << 6) | cb16) ^ cxor;
      bf16x8 af[4], bfr[4];
#pragma unroll
      for (int m = 0; m < 4; ++m)
        af[m] = *reinterpret_cast<const bf16x8*>((const char*)As + (size_t)(ra + m * 16) * 128 + cb);
#pragma unroll
      for (int n = 0; n < 4; ++n)
        bfr[n] = *reinterpret_cast<const bf16x8*>((const char*)Bs + (size_t)(rb + n * 16) * 128 + cb);
#pragma unroll
      for (int m = 0; m < 4; ++m)
#pragma unroll
        for (int n = 0; n < 4; ++n)
          acc[m][n] = __builtin_amdgcn_mfma_f32_16x16x32_bf16(af[m], bfr[n], acc[m][n], 0, 0, 0);
    }
    __syncthreads();
  }

  // fire-and-forget: zero this block's 128x128 S_ sub-tile (NT, coalesced)
  {
    f32x4 z = {0.f, 0.f, 0.f, 0.f};
    int r0 = t >> 5;            // 0..7
    int c4 = t & 31;            // float4 col within the 128-float row chunk
#pragma unroll
    for (int p = 0; p < 16; ++p) {
      int row = p * 8 + r0;
      __builtin_nontemporal_store(z,
          reinterpret_cast<f32x4*>(S + (size_t)(bb + row) * N_DIM + bn) + c4);
    }
  }

  // epilogue: wave-aggregated LDS append of candidates (v > THR)
#pragma unroll
  for (int n = 0; n < 4; ++n) {
    int col = bn + wc * 64 + n * 16 + (ln & 15);
    float lb = lbias[col];
#pragma unroll
    for (int m = 0; m < 4; ++m) {
      int rl0 = wr * 64 + m * 16 + (ln >> 4) * 4;
#pragma unroll
      for (int j = 0; j < 4; ++j) {
        float v = acc[m][n][j] + lb;
        bool pred = (v > THR_INIT);
        unsigned long long mask = __ballot(pred);
        if (pred) {
          int lead = __ffsll((unsigned long long)mask) - 1;
          int base = 0;
          if (ln == lead) base = atomicAdd(&bcnt, (int)__popcll(mask));
          base = __shfl(base, lead);
          int p = base + (int)__popcll(mask & ((1ull << ln) - 1ull));
          if (p < BCAP) {
            bl_pk[p] = pack_key(f2b(v), col);
            bl_row[p] = rl0 + j;
          }
        }
      }
    }
  }
  __syncthreads();

  int nb = bcnt < BCAP ? bcnt : BCAP;
  for (int e = t; e < nb; e += 256)
    bl_slot[e] = atomicAdd(&rcnt[bl_row[e]], 1);
  __syncthreads();

  if (t < 128) {
    int c = rcnt[t];
    int add = c + ((bcnt > BCAP) ? 100000 : 0);   // overflow -> force fallback
    rbase[t] = add ? atomicAdd(&cnt[bb + t], add) : 0;
  }
  __syncthreads();

  for (int e = t; e < nb; e += 256) {
    int rl = bl_row[e];
    int g = rbase[rl] + bl_slot[e];
    if (g < CAP) lists[(size_t)(bb + rl) * CAP + g] = bl_pk[e];
  }
}

// ---- Kernel 3: select (safe/borderline split) + scatter + decode -----------
// Safe candidates (key > v32+margin) are provably in ref's top-32: value =
// key-decoded f32 (err ~0.03 << 0.118 threshold). Borderline (~16) get
// exact f64 dots. f32 D decode (bf16-D measured no gain: latency-bound).
__global__ __launch_bounds__(256) void select_output(
    const unsigned* __restrict__ lists, const int* __restrict__ cnt,
    const float* __restrict__ X, const float* __restrict__ pbias,
    const float* __restrict__ W,            // f32 W_enc
    const unsigned short* __restrict__ Xcb, // bf16 inputs (fallback only)
    const unsigned short* __restrict__ Wb,
    const float* __restrict__ lbias,
    const float* __restrict__ Dmat,
    float* __restrict__ S, float* __restrict__ Xout)
{
  __shared__ unsigned list[CAP];
  __shared__ float xrow[M_DIM];
  __shared__ int ridx[256];
  __shared__ double rval[256];
  __shared__ float s_v32;
  __shared__ int s_rc, s_cnt, s_ns;
  __shared__ int si[K_TOP];
  __shared__ float sv[K_TOP];

  int b = blockIdx.x;
  int t = threadIdx.x;
  int ln = t & 63, w = t >> 6;

  for (int i = t; i < M_DIM; i += 256)
    xrow[i] = X[(size_t)b * M_DIM + i] - pbias[i];
  if (t < K_TOP) { si[t] = t; sv[t] = 0.f; }
  if (t == 0) { s_v32 = -1.0e30f; s_rc = 0; s_ns = 0; }

  int count = cnt[b];
  int nc;
  if (count >= 48 && count <= CAP) {
    for (int i = t; i < count; i += 256) list[i] = lists[(size_t)b * CAP + i];
    nc = count;
    __syncthreads();
  } else {
    // near-impossible fallback: recompute bf16-proxy row, adaptive collect
    float pv[N_DIM / 256];
#pragma unroll 1
    for (int q = 0; q < N_DIM / 256; ++q) {
      int n = t + q * 256;
      const unsigned short* wrp = Wb + (size_t)n * M_DIM;
      const unsigned short* xbp = Xcb + (size_t)b * M_DIM;
      float s = 0.f;
      for (int k = 0; k < M_DIM; ++k) s = fmaf(b2f(xbp[k]), b2f(wrp[k]), s);
      pv[q] = s + lbias[n];
    }
    float thr = THR_INIT;
    for (int it = 0; it < 8; ++it) {
      __syncthreads();
      if (t == 0) s_cnt = 0;
      __syncthreads();
#pragma unroll 1
      for (int q = 0; q < N_DIM / 256; ++q) {
        if (pv[q] > thr) {
          int p = atomicAdd(&s_cnt, 1);
          if (p < CAP) list[p] = pack_key(f2b(pv[q]), t + q * 256);
        }
      }
      __syncthreads();
      int c = s_cnt;
      if (c > CAP)      { thr += 0.35f; continue; }
      else if (c < 48)  { thr -= 0.60f; continue; }
      break;
    }
    nc = s_cnt < CAP ? s_cnt : CAP;
    __syncthreads();
  }

  // rank by packed key -> v32 (keys unique; exactly one has rank K_TOP-1)
  for (int q = t; q < nc; q += 256) {
    unsigned me = list[q];
    int r = 0;
    for (int j = 0; j < nc; ++j) r += (list[j] > me);
    if (r == K_TOP - 1) s_v32 = key_val(me);
  }
  __syncthreads();

  float v32 = s_v32;
  float vplus = v32 + RESCUE_MARGIN;
  float vminus = v32 - RESCUE_MARGIN;

  // partition: safe -> direct slot (deterministic pk-rank among safe);
  // borderline -> exact-dot list
  for (int q = t; q < nc; q += 256) {
    unsigned me = list[q];
    float kv = key_val(me);
    if (kv > vplus) {
      int r = 0;
      for (int j = 0; j < nc; ++j) {
        unsigned o = list[j];
        if (o > me && key_val(o) > vplus) ++r;
      }
      si[r] = (int)(me & 0xFFFF);    // r <= 30 guaranteed (kv>v32 => pk-rank<32)
      sv[r] = kv;                    // >2.2 > 0, no ReLU clamp needed
      atomicAdd(&s_ns, 1);
    } else if (kv >= vminus) {
      int p = atomicAdd(&s_rc, 1);
      if (p < 256) ridx[p] = (int)(me & 0xFFFF);
    }
  }
  __syncthreads();
  int ns = s_ns;
  int nr = s_rc < 256 ? s_rc : 256;
  int need = K_TOP - ns;             // >= 1 (rank-31 key is always borderline)

  // exact f64 dot per borderline candidate (one wave each), float4 W reads
  for (int cc = w; cc < nr; cc += 4) {
    int n = ridx[cc];
    const f32x4* w4 = reinterpret_cast<const f32x4*>(W + (size_t)n * M_DIM);
    double s = 0.0;
#pragma unroll
    for (int j = 0; j < M_DIM / 256; ++j) {     // 3 iters: lane ln + 64*j
      int i4 = ln + 64 * j;
      f32x4 wv = w4[i4];
      int k0 = i4 * 4;
      s += (double)xrow[k0]     * (double)wv.x;
      s += (double)xrow[k0 + 1] * (double)wv.y;
      s += (double)xrow[k0 + 2] * (double)wv.z;
      s += (double)xrow[k0 + 3] * (double)wv.w;
    }
    for (int off = 32; off > 0; off >>= 1) s += __shfl_down(s, off);
    if (ln == 0) rval[cc] = s + (double)lbias[n];
  }
  __syncthreads();

  // borderline top-(need) by (val desc, idx asc); ranks unique
  if (t < nr) {
    double mv = rval[t];
    int mi = ridx[t];
    int r = 0;
    for (int j = 0; j < nr; ++j) {
      double v = rval[j];
      if (v > mv || (v == mv && ridx[j] < mi)) ++r;
    }
    if (r < need) {
      si[ns + r] = mi;
      sv[ns + r] = fmaxf((float)mv, 0.0f);   // ReLU
    }
  }
  __syncthreads();

  // scatter the 32 values into the pre-zeroed S_ row
  if (t < K_TOP)
    S[(size_t)b * N_DIM + si[t]] = sv[t];

  // decode: X_[b,:] = sum_j val_j * D[idx_j,:] + pre_bias (float4, t<192)
  if (t < M_DIM / 4) {
    f32x4 a = {0.f, 0.f, 0.f, 0.f};
#pragma unroll 4
    for (int j = 0; j < K_TOP; ++j) {
      float v = sv[j];
      f32x4 d = reinterpret_cast<const f32x4*>(Dmat + (size_t)si[j] * M_DIM)[t];
      a.x = fmaf(v, d.x, a.x); a.y = fmaf(v, d.y, a.y);
      a.z = fmaf(v, d.z, a.z); a.w = fmaf(v, d.w, a.w);
    }
    f32x4 p = reinterpret_cast<const f32x4*>(pbias)[t];
    a.x += p.x; a.y += p.y; a.z += p.z; a.w += p.w;
    __builtin_nontemporal_store(a, reinterpret_cast<f32x4*>(Xout + (size_t)b * M_DIM) + t);
  }
}

extern "C" void kernel_launch(void* const* d_in, const int* in_sizes, int n_in,
                              void* d_out, int out_size, void* d_ws, size_t ws_size,
                              hipStream_t stream) {
  const float* X  = (const float*)d_in[0];
  const float* Dm = (const float*)d_in[1];
  const float* We = (const float*)d_in[2];
  const float* lb = (const float*)d_in[3];
  const float* pb = (const float*)d_in[4];

  float* S  = (float*)d_out;                        // S_ region, f32 [4096][16384]
  float* Xo = S + (size_t)B_DIM * N_DIM;            // X_ region, f32 [4096][768]

  // ws layout (39,862,272 B used; 40.9 MB proven available since round 3)
  char* ws = (char*)d_ws;
  unsigned short* Xcb   = (unsigned short*)(ws);               //  6,291,456 B
  unsigned short* Wb    = (unsigned short*)(ws +  6291456);    // 25,165,824 B
  unsigned*       lists = (unsigned*)      (ws + 31457280);    //  8,388,608 B
  int*            cnt   = (int*)           (ws + 39845888);    //     16,384 B

  prep_kernel<<<dim3(1024), dim3(256), 0, stream>>>(X, We, pb, Xcb, Wb, cnt);
  gemm_enc<<<dim3(4096), dim3(256), 0, stream>>>(Xcb, Wb, lb, lists, cnt, S);
  select_output<<<dim3(4096), dim3(256), 0, stream>>>(lists, cnt, X, pb, We, Xcb, Wb, lb, Dm, S, Xo);
}

// Round 19
// 283.690 us; speedup vs baseline: 1.1345x; 1.0204x over previous
//
#include <hip/hip_runtime.h>
#include <hip/hip_bf16.h>

#define B_DIM 4096
#define M_DIM 768
#define N_DIM 16384
#define K_TOP 32
#define CAP 512
#define BCAP 512
#define THR_INIT 2.2f
#define RESCUE_MARGIN 0.09375f

typedef __bf16 bf16x8 __attribute__((ext_vector_type(8)));
typedef float  f32x4  __attribute__((ext_vector_type(4)));

static __device__ __forceinline__ unsigned short f2b(float f) {
  union { float f; unsigned u; } a; a.f = f;
  unsigned u = a.u;
  u += 0x7FFFu + ((u >> 16) & 1u);   // round-to-nearest-even
  return (unsigned short)(u >> 16);
}
static __device__ __forceinline__ float b2f(unsigned short h) {
  union { unsigned u; float f; } a; a.u = ((unsigned)h) << 16;
  return a.f;
}
// monotonic 16-bit key in high bits, col idx in low bits
static __device__ __forceinline__ unsigned pack_key(unsigned short h, int idx) {
  unsigned short k = (h & 0x8000) ? (unsigned short)~h : (unsigned short)(h | 0x8000);
  return ((unsigned)k << 16) | (unsigned)(idx & 0xFFFF);
}
static __device__ __forceinline__ float key_val(unsigned pk) {
  unsigned short k = (unsigned short)(pk >> 16);
  unsigned short h = (k & 0x8000) ? (unsigned short)(k ^ 0x8000) : (unsigned short)~k;
  return b2f(h);
}

// ------------- Kernel 1: prep (center+cast X, cast W, zero counters) --------
__global__ __launch_bounds__(256) void prep_kernel(
    const float* __restrict__ X, const float* __restrict__ W,
    const float* __restrict__ pre_bias,
    unsigned short* __restrict__ Xcb, unsigned short* __restrict__ Wb,
    int* __restrict__ cnt)
{
  const int NX4 = B_DIM * M_DIM / 4;
  const int NW4 = N_DIM * M_DIM / 4;
  int stride = gridDim.x * blockDim.x;
  int i0 = blockIdx.x * blockDim.x + threadIdx.x;
  for (int i = i0; i < NX4; i += stride) {
    float4 x = reinterpret_cast<const float4*>(X)[i];
    int c4 = i % (M_DIM / 4);
    float4 pb = reinterpret_cast<const float4*>(pre_bias)[c4];
    ushort4 b;
    b.x = f2b(x.x - pb.x); b.y = f2b(x.y - pb.y);
    b.z = f2b(x.z - pb.z); b.w = f2b(x.w - pb.w);
    reinterpret_cast<ushort4*>(Xcb)[i] = b;
  }
  for (int i = i0; i < NW4; i += stride) {
    float4 x = reinterpret_cast<const float4*>(W)[i];
    ushort4 b; b.x = f2b(x.x); b.y = f2b(x.y); b.z = f2b(x.z); b.w = f2b(x.w);
    reinterpret_cast<ushort4*>(Wb)[i] = b;
  }
  for (int i = i0; i < B_DIM; i += stride) cnt[i] = 0;
}

// ---- Kernel 2: encoder GEMM (BK=64, XOR-swizzled LDS, r8 XCD swizzle) ------
// Tail NT zeroing (best placement) + two-pass prefix-scan candidate collect
// (replaces 64 serialized ballot rounds; list order is semantically free).
__global__ __launch_bounds__(256, 3) void gemm_enc(
    const unsigned short* __restrict__ A,   // Xc bf16 [4096][768]
    const unsigned short* __restrict__ Bw,  // W_enc bf16 [16384][768]
    const float* __restrict__ lbias,
    unsigned* __restrict__ lists,           // [4096][512] packed key|col
    int* __restrict__ cnt,                  // [4096]
    float* __restrict__ S)                  // dense S_ region: zero our subtile
{
  __shared__ __align__(16) unsigned short As[128 * 64];
  __shared__ __align__(16) unsigned short Bs[128 * 64];
  __shared__ unsigned bl_pk[BCAP];
  __shared__ int bl_row[BCAP];
  __shared__ int bl_slot[BCAP];
  __shared__ int rcnt[128];
  __shared__ int rbase[128];
  __shared__ int bcnt;

  int t = threadIdx.x;
  int ln = t & 63;
  int w = t >> 6;
  int wr = w >> 1, wc = w & 1;

  if (t == 0) bcnt = 0;
  if (t < 128) rcnt[t] = 0;

  // round-8 XCD swizzle: contiguous chunk per XCD, tx fast within ty
  int lid = blockIdx.x;
  int swz = (lid & 7) * (4096 / 8) + (lid >> 3);
  int ty = swz >> 7;        // 0..31
  int tx = swz & 127;       // 0..127
  int bb = ty * 128, bn = tx * 128;

  int srow = t >> 3;                          // 0..31 local row in 32-row chunk
  int scol = (((t & 7) ^ ((t >> 3) & 7)) << 4);
  const char* gAb = (const char*)A  + (size_t)(bb + srow) * (M_DIM * 2) + scol;
  const char* gBb = (const char*)Bw + (size_t)(bn + srow) * (M_DIM * 2) + scol;
  char* lA = (char*)As + t * 16;
  char* lB = (char*)Bs + t * 16;
  const int CH = 32 * M_DIM * 2;              // 32-row global chunk stride

  f32x4 acc[4][4] = {};

  int cxor = (ln & 7) << 4;
  int cb16 = (ln >> 4) << 4;
  int ra = wr * 64 + (ln & 15);
  int rb = wc * 64 + (ln & 15);

  for (int kb = 0; kb < M_DIM * 2; kb += 128) {   // 64 cols * 2B per step
#pragma unroll
    for (int q = 0; q < 4; ++q) {
      __builtin_amdgcn_global_load_lds(
          (__attribute__((address_space(1))) void*)(gAb + q * CH + kb),
          (__attribute__((address_space(3))) void*)(lA + q * 4096), 16, 0, 0);
      __builtin_amdgcn_global_load_lds(
          (__attribute__((address_space(1))) void*)(gBb + q * CH + kb),
          (__attribute__((address_space(3))) void*)(lB + q * 4096), 16, 0, 0);
    }
    __syncthreads();

#pragma unroll
    for (int g = 0; g < 2; ++g) {
      int cb = ((g << 6) | cb16) ^ cxor;
      bf16x8 af[4], bfr[4];
#pragma unroll
      for (int m = 0; m < 4; ++m)
        af[m] = *reinterpret_cast<const bf16x8*>((const char*)As + (size_t)(ra + m * 16) * 128 + cb);
#pragma unroll
      for (int n = 0; n < 4; ++n)
        bfr[n] = *reinterpret_cast<const bf16x8*>((const char*)Bs + (size_t)(rb + n * 16) * 128 + cb);
#pragma unroll
      for (int m = 0; m < 4; ++m)
#pragma unroll
        for (int n = 0; n < 4; ++n)
          acc[m][n] = __builtin_amdgcn_mfma_f32_16x16x32_bf16(af[m], bfr[n], acc[m][n], 0, 0, 0);
    }
    __syncthreads();
  }

  // fire-and-forget: zero this block's 128x128 S_ sub-tile (NT, coalesced)
  {
    f32x4 z = {0.f, 0.f, 0.f, 0.f};
    int r0 = t >> 5;            // 0..7
    int c4 = t & 31;            // float4 col within the 128-float row chunk
#pragma unroll
    for (int p = 0; p < 16; ++p) {
      int row = p * 8 + r0;
      __builtin_nontemporal_store(z,
          reinterpret_cast<f32x4*>(S + (size_t)(bb + row) * N_DIM + bn) + c4);
    }
  }

  // epilogue: two-pass prefix-scan candidate collect (v > THR)
  float lbv[4];
#pragma unroll
  for (int n = 0; n < 4; ++n)
    lbv[n] = lbias[bn + wc * 64 + n * 16 + (ln & 15)];

  // pass 1: per-thread count
  int cl = 0;
#pragma unroll
  for (int n = 0; n < 4; ++n)
#pragma unroll
    for (int m = 0; m < 4; ++m)
#pragma unroll
      for (int j = 0; j < 4; ++j)
        cl += (acc[m][n][j] + lbv[n] > THR_INIT) ? 1 : 0;

  // wave inclusive scan -> exclusive prefix; one LDS atomic per wave
  int incl = cl;
#pragma unroll
  for (int o = 1; o < 64; o <<= 1) {
    int up = __shfl_up(incl, o);
    incl += (ln >= o) ? up : 0;
  }
  int wtot = __shfl(incl, 63);
  int excl = incl - cl;
  int base = 0;
  if (ln == 63) base = atomicAdd(&bcnt, wtot);
  base = __shfl(base, 63);
  int mypos = base + excl;

  // pass 2: re-walk acc, write at mypos + running (no runtime-indexed arrays)
  {
    int k = 0;
#pragma unroll
    for (int n = 0; n < 4; ++n) {
      int col = bn + wc * 64 + n * 16 + (ln & 15);
#pragma unroll
      for (int m = 0; m < 4; ++m) {
        int rl0 = wr * 64 + m * 16 + (ln >> 4) * 4;
#pragma unroll
        for (int j = 0; j < 4; ++j) {
          float v = acc[m][n][j] + lbv[n];
          if (v > THR_INIT) {
            int p = mypos + k;
            if (p < BCAP) { bl_pk[p] = pack_key(f2b(v), col); bl_row[p] = rl0 + j; }
            ++k;
          }
        }
      }
    }
  }
  __syncthreads();

  int nb = bcnt < BCAP ? bcnt : BCAP;
  for (int e = t; e < nb; e += 256)
    bl_slot[e] = atomicAdd(&rcnt[bl_row[e]], 1);
  __syncthreads();

  if (t < 128) {
    int c = rcnt[t];
    int add = c + ((bcnt > BCAP) ? 100000 : 0);   // overflow -> force fallback
    rbase[t] = add ? atomicAdd(&cnt[bb + t], add) : 0;
  }
  __syncthreads();

  for (int e = t; e < nb; e += 256) {
    int rl = bl_row[e];
    int g = rbase[rl] + bl_slot[e];
    if (g < CAP) lists[(size_t)(bb + rl) * CAP + g] = bl_pk[e];
  }
}

// ---- Kernel 3: select (safe/borderline split) + scatter + decode -----------
// Safe candidates (key > v32+margin) are provably in ref's top-32: value =
// key-decoded f32 (err ~0.03 << 0.118 threshold). Borderline (~16) get
// exact f64 dots.
__global__ __launch_bounds__(256) void select_output(
    const unsigned* __restrict__ lists, const int* __restrict__ cnt,
    const float* __restrict__ X, const float* __restrict__ pbias,
    const float* __restrict__ W,            // f32 W_enc
    const unsigned short* __restrict__ Xcb, // bf16 inputs (fallback only)
    const unsigned short* __restrict__ Wb,
    const float* __restrict__ lbias,
    const float* __restrict__ Dmat,
    float* __restrict__ S, float* __restrict__ Xout)
{
  __shared__ unsigned list[CAP];
  __shared__ float xrow[M_DIM];
  __shared__ int ridx[256];
  __shared__ double rval[256];
  __shared__ float s_v32;
  __shared__ int s_rc, s_cnt, s_ns;
  __shared__ int si[K_TOP];
  __shared__ float sv[K_TOP];

  int b = blockIdx.x;
  int t = threadIdx.x;
  int ln = t & 63, w = t >> 6;

  for (int i = t; i < M_DIM; i += 256)
    xrow[i] = X[(size_t)b * M_DIM + i] - pbias[i];
  if (t < K_TOP) { si[t] = t; sv[t] = 0.f; }
  if (t == 0) { s_v32 = -1.0e30f; s_rc = 0; s_ns = 0; }

  int count = cnt[b];
  int nc;
  if (count >= 48 && count <= CAP) {
    for (int i = t; i < count; i += 256) list[i] = lists[(size_t)b * CAP + i];
    nc = count;
    __syncthreads();
  } else {
    // near-impossible fallback: recompute bf16-proxy row, adaptive collect
    float pv[N_DIM / 256];
#pragma unroll 1
    for (int q = 0; q < N_DIM / 256; ++q) {
      int n = t + q * 256;
      const unsigned short* wrp = Wb + (size_t)n * M_DIM;
      const unsigned short* xbp = Xcb + (size_t)b * M_DIM;
      float s = 0.f;
      for (int k = 0; k < M_DIM; ++k) s = fmaf(b2f(xbp[k]), b2f(wrp[k]), s);
      pv[q] = s + lbias[n];
    }
    float thr = THR_INIT;
    for (int it = 0; it < 8; ++it) {
      __syncthreads();
      if (t == 0) s_cnt = 0;
      __syncthreads();
#pragma unroll 1
      for (int q = 0; q < N_DIM / 256; ++q) {
        if (pv[q] > thr) {
          int p = atomicAdd(&s_cnt, 1);
          if (p < CAP) list[p] = pack_key(f2b(pv[q]), t + q * 256);
        }
      }
      __syncthreads();
      int c = s_cnt;
      if (c > CAP)      { thr += 0.35f; continue; }
      else if (c < 48)  { thr -= 0.60f; continue; }
      break;
    }
    nc = s_cnt < CAP ? s_cnt : CAP;
    __syncthreads();
  }

  // rank by packed key -> v32 (keys unique; exactly one has rank K_TOP-1)
  for (int q = t; q < nc; q += 256) {
    unsigned me = list[q];
    int r = 0;
    for (int j = 0; j < nc; ++j) r += (list[j] > me);
    if (r == K_TOP - 1) s_v32 = key_val(me);
  }
  __syncthreads();

  float v32 = s_v32;
  float vplus = v32 + RESCUE_MARGIN;
  float vminus = v32 - RESCUE_MARGIN;

  // partition: safe -> direct slot (deterministic pk-rank among safe);
  // borderline -> exact-dot list
  for (int q = t; q < nc; q += 256) {
    unsigned me = list[q];
    float kv = key_val(me);
    if (kv > vplus) {
      int r = 0;
      for (int j = 0; j < nc; ++j) {
        unsigned o = list[j];
        if (o > me && key_val(o) > vplus) ++r;
      }
      si[r] = (int)(me & 0xFFFF);    // r <= 30 guaranteed (kv>v32 => pk-rank<32)
      sv[r] = kv;                    // >2.2 > 0, no ReLU clamp needed
      atomicAdd(&s_ns, 1);
    } else if (kv >= vminus) {
      int p = atomicAdd(&s_rc, 1);
      if (p < 256) ridx[p] = (int)(me & 0xFFFF);
    }
  }
  __syncthreads();
  int ns = s_ns;
  int nr = s_rc < 256 ? s_rc : 256;
  int need = K_TOP - ns;             // >= 1 (rank-31 key is always borderline)

  // exact f64 dot per borderline candidate (one wave each), float4 W reads
  for (int cc = w; cc < nr; cc += 4) {
    int n = ridx[cc];
    const f32x4* w4 = reinterpret_cast<const f32x4*>(W + (size_t)n * M_DIM);
    double s = 0.0;
#pragma unroll
    for (int j = 0; j < M_DIM / 256; ++j) {     // 3 iters: lane ln + 64*j
      int i4 = ln + 64 * j;
      f32x4 wv = w4[i4];
      int k0 = i4 * 4;
      s += (double)xrow[k0]     * (double)wv.x;
      s += (double)xrow[k0 + 1] * (double)wv.y;
      s += (double)xrow[k0 + 2] * (double)wv.z;
      s += (double)xrow[k0 + 3] * (double)wv.w;
    }
    for (int off = 32; off > 0; off >>= 1) s += __shfl_down(s, off);
    if (ln == 0) rval[cc] = s + (double)lbias[n];
  }
  __syncthreads();

  // borderline top-(need) by (val desc, idx asc); ranks unique
  if (t < nr) {
    double mv = rval[t];
    int mi = ridx[t];
    int r = 0;
    for (int j = 0; j < nr; ++j) {
      double v = rval[j];
      if (v > mv || (v == mv && ridx[j] < mi)) ++r;
    }
    if (r < need) {
      si[ns + r] = mi;
      sv[ns + r] = fmaxf((float)mv, 0.0f);   // ReLU
    }
  }
  __syncthreads();

  // scatter the 32 values into the pre-zeroed S_ row
  if (t < K_TOP)
    S[(size_t)b * N_DIM + si[t]] = sv[t];

  // decode: X_[b,:] = sum_j val_j * D[idx_j,:] + pre_bias (float4, t<192)
  if (t < M_DIM / 4) {
    f32x4 a = {0.f, 0.f, 0.f, 0.f};
#pragma unroll 4
    for (int j = 0; j < K_TOP; ++j) {
      float v = sv[j];
      f32x4 d = reinterpret_cast<const f32x4*>(Dmat + (size_t)si[j] * M_DIM)[t];
      a.x = fmaf(v, d.x, a.x); a.y = fmaf(v, d.y, a.y);
      a.z = fmaf(v, d.z, a.z); a.w = fmaf(v, d.w, a.w);
    }
    f32x4 p = reinterpret_cast<const f32x4*>(pbias)[t];
    a.x += p.x; a.y += p.y; a.z += p.z; a.w += p.w;
    __builtin_nontemporal_store(a, reinterpret_cast<f32x4*>(Xout + (size_t)b * M_DIM) + t);
  }
}

extern "C" void kernel_launch(void* const* d_in, const int* in_sizes, int n_in,
                              void* d_out, int out_size, void* d_ws, size_t ws_size,
                              hipStream_t stream) {
  const float* X  = (const float*)d_in[0];
  const float* Dm = (const float*)d_in[1];
  const float* We = (const float*)d_in[2];
  const float* lb = (const float*)d_in[3];
  const float* pb = (const float*)d_in[4];

  float* S  = (float*)d_out;                        // S_ region, f32 [4096][16384]
  float* Xo = S + (size_t)B_DIM * N_DIM;            // X_ region, f32 [4096][768]

  // ws layout (39,862,272 B used; 40.9 MB proven available since round 3)
  char* ws = (char*)d_ws;
  unsigned short* Xcb   = (unsigned short*)(ws);               //  6,291,456 B
  unsigned short* Wb    = (unsigned short*)(ws +  6291456);    // 25,165,824 B
  unsigned*       lists = (unsigned*)      (ws + 31457280);    //  8,388,608 B
  int*            cnt   = (int*)           (ws + 39845888);    //     16,384 B

  prep_kernel<<<dim3(1024), dim3(256), 0, stream>>>(X, We, pb, Xcb, Wb, cnt);
  gemm_enc<<<dim3(4096), dim3(256), 0, stream>>>(Xcb, Wb, lb, lists, cnt, S);
  select_output<<<dim3(4096), dim3(256), 0, stream>>>(lists, cnt, X, pb, We, Xcb, Wb, lb, Dm, S, Xo);
}